// Round 2
// baseline (3723.770 us; speedup 1.0000x reference)
//
#include <hip/hip_runtime.h>
#include <cstdint>
#include <cstddef>

// B=1, S=64, L_ENC=64, E=512, Z=512, H=1024, NL=2, V=32000
// Outputs flat: logits [64][32000], attn_out [64][2048], hT [2][1024], cT [2][1024]

#define OUT_LOGITS 0
#define OUT_ATTN   2048000
#define OUT_HT     (2048000+131072)
#define OUT_CT     (OUT_HT+2048)
#define RB 512   // blocks in the persistent recurrence kernel

typedef short short8v __attribute__((ext_vector_type(8)));
typedef float floatx4 __attribute__((ext_vector_type(4)));

__device__ __forceinline__ float sigf_(float x) { return 1.0f / (1.0f + expf(-x)); }
__device__ __forceinline__ unsigned short f2bf(float x) {
    unsigned u = __float_as_uint(x);
    return (unsigned short)((u + 0x7fffu + ((u >> 16) & 1u)) >> 16);   // RNE
}
__device__ __forceinline__ unsigned pk2(float lo, float hi) {
    return (unsigned)f2bf(lo) | ((unsigned)f2bf(hi) << 16);
}
__device__ __forceinline__ float blo(unsigned u) { return __uint_as_float(u << 16); }
__device__ __forceinline__ float bhi(unsigned u) { return __uint_as_float(u & 0xffff0000u); }

// ---------------------------------------------------------------------------
// Build X = concat(dec, z) as bf16 [64][1024]
// ---------------------------------------------------------------------------
__global__ __launch_bounds__(256) void k_prep_x(
    const float* __restrict__ dec, const float* __restrict__ z,
    unsigned short* __restrict__ Xbf)
{
    int i = blockIdx.x * 256 + threadIdx.x;      // grid 256 -> 65536
    int t = i >> 10, k = i & 1023;
    float v = (k < 512) ? dec[t * 512 + k] : z[k - 512];
    Xbf[i] = f2bf(v);
}

// ---------------------------------------------------------------------------
// Generic MFMA GEMM: out[t][m] = sum_k A[m][k]*B[t][k] + bias1[m] (+bias2[m])
// A fp32 [M][1024] (converted to bf16 in-kernel), B bf16 [64][1024].
// Block = 4 waves, each wave: 16 m-rows x 64 t. Grid = M/64.
// MFMA 16x16x32 bf16: A[m=lane&15][k=(lane>>4)*8+j]; B[n=lane&15][k=quad*8+j];
// D row(m)=(lane>>4)*4+reg, col(n)=lane&15.   [per m89/m91/m120 verified maps]
// ---------------------------------------------------------------------------
__global__ __launch_bounds__(256) void k_gemm(
    const float* __restrict__ A, const unsigned short* __restrict__ Bb,
    const float* __restrict__ bias1, const float* __restrict__ bias2,
    float* __restrict__ out, int M)
{
    const int tid = threadIdx.x, wave = tid >> 6, lane = tid & 63;
    const int m0 = blockIdx.x * 64 + wave * 16;
    const int mr = lane & 15, kq = lane >> 4;
    const float* arow = A + (size_t)(m0 + mr) * 1024 + kq * 8;
    const unsigned short* brow = Bb + (size_t)mr * 1024 + kq * 8;
    floatx4 acc[4] = {};

    for (int kk = 0; kk < 1024; kk += 32) {
        float4 a0 = *(const float4*)(arow + kk);
        float4 a1 = *(const float4*)(arow + kk + 4);
        short8v af;
        af[0] = (short)f2bf(a0.x); af[1] = (short)f2bf(a0.y);
        af[2] = (short)f2bf(a0.z); af[3] = (short)f2bf(a0.w);
        af[4] = (short)f2bf(a1.x); af[5] = (short)f2bf(a1.y);
        af[6] = (short)f2bf(a1.z); af[7] = (short)f2bf(a1.w);
        #pragma unroll
        for (int g = 0; g < 4; ++g) {
            short8v bf = *(const short8v*)(brow + (size_t)g * 16 * 1024 + kk);
            acc[g] = __builtin_amdgcn_mfma_f32_16x16x32_bf16(af, bf, acc[g], 0, 0, 0);
        }
    }
    const int mo = m0 + (kq << 2);                 // m = quad*4 + reg
    float4 bv = *(const float4*)(bias1 + mo);
    if (bias2) {
        float4 b2 = *(const float4*)(bias2 + mo);
        bv.x += b2.x; bv.y += b2.y; bv.z += b2.z; bv.w += b2.w;
    }
    #pragma unroll
    for (int g = 0; g < 4; ++g) {
        const int t = g * 16 + mr;
        float4 o;
        o.x = acc[g][0] + bv.x; o.y = acc[g][1] + bv.y;
        o.z = acc[g][2] + bv.z; o.w = acc[g][3] + bv.w;
        *(float4*)(out + (size_t)t * M + mo) = o;
    }
}

// ---------------------------------------------------------------------------
// Persistent cooperative recurrence kernel. 512 blocks x 256 threads.
// Block b owns units u = {2b, 2b+1} of BOTH layers.
//   waves 0,1 -> layer0 unit u (4 gate rows of W_hh0, 1024 each) in LDS bf16
//   waves 2,3 -> layer1 unit u (4 gate rows of [W_ih1|W_hh1], 2048 each)
// 65 pipeline stages: stage k computes L0@t=k and L1@t=k-1; one grid barrier
// between stages (per-stage arrival counter + release/acquire gen).
// ---------------------------------------------------------------------------
__global__ __launch_bounds__(256, 2) void k_recur(
    const float* __restrict__ W_ih, const float* __restrict__ W_hh,
    const float* __restrict__ b_ih, const float* __restrict__ b_hh,
    const float* __restrict__ h_init, const float* __restrict__ c_init,
    const float* __restrict__ Gin0,
    float* __restrict__ h0buf,   // [2][1024] ping-pong
    float* __restrict__ h1buf,   // [2][1024]
    unsigned* __restrict__ bar,  // cnt[0..64], gen at [72]
    float* __restrict__ attn,    // [64][2048] (outs into first 1024 cols)
    unsigned short* __restrict__ outs_bf, // [64][1024]
    float* __restrict__ out_ht, float* __restrict__ out_ct)
{
    __shared__ uint32_t wls[8 * 512 + 8 * 1024];   // 48 KB packed bf16 pairs
    const int tid = threadIdx.x, wave = tid >> 6, lane = tid & 63;
    const bool isL1 = wave >= 2;
    const int u = blockIdx.x * 2 + (wave & 1);
    uint32_t* wbase = isL1 ? (wls + 8 * 512 + (wave & 1) * 4 * 1024)
                           : (wls + (wave & 1) * 4 * 512);

    // ---- load + convert weights into LDS (identity pair layout: pair p at dword p) ----
    if (!isL1) {
        #pragma unroll
        for (int q = 0; q < 4; ++q) {
            const float* row = W_hh + (size_t)(q * 1024 + u) * 1024;
            uint32_t* dst = wbase + q * 512;
            #pragma unroll
            for (int jq = 0; jq < 2; ++jq) {
                float4 a = *(const float4*)(row + 512 * jq + 8 * lane);
                float4 b = *(const float4*)(row + 512 * jq + 8 * lane + 4);
                uint4 p;
                p.x = pk2(a.x, a.y); p.y = pk2(a.z, a.w);
                p.z = pk2(b.x, b.y); p.w = pk2(b.z, b.w);
                *(uint4*)(dst + jq * 256 + lane * 4) = p;
            }
        }
    } else {
        #pragma unroll
        for (int q = 0; q < 4; ++q) {
            const float* rowi = W_ih + (size_t)4096 * 1024 + (size_t)(q * 1024 + u) * 1024;
            const float* rowh = W_hh + (size_t)4096 * 1024 + (size_t)(q * 1024 + u) * 1024;
            uint32_t* dst = wbase + q * 1024;
            #pragma unroll
            for (int jq = 0; jq < 2; ++jq) {
                float4 a = *(const float4*)(rowi + 512 * jq + 8 * lane);
                float4 b = *(const float4*)(rowi + 512 * jq + 8 * lane + 4);
                uint4 p;
                p.x = pk2(a.x, a.y); p.y = pk2(a.z, a.w);
                p.z = pk2(b.x, b.y); p.w = pk2(b.z, b.w);
                *(uint4*)(dst + jq * 256 + lane * 4) = p;
                a = *(const float4*)(rowh + 512 * jq + 8 * lane);
                b = *(const float4*)(rowh + 512 * jq + 8 * lane + 4);
                p.x = pk2(a.x, a.y); p.y = pk2(a.z, a.w);
                p.z = pk2(b.x, b.y); p.w = pk2(b.z, b.w);
                *(uint4*)(dst + 512 + jq * 256 + lane * 4) = p;
            }
        }
    }
    __syncthreads();

    // per-wave lane0 state
    float cst = 0.f, bi0 = 0.f, bi1 = 0.f, bi2 = 0.f, bi3 = 0.f;
    if (lane == 0) {
        cst = c_init[(isL1 ? 1024 : 0) + u];
        if (isL1) {
            bi0 = b_ih[4096 + u]        + b_hh[4096 + u];
            bi1 = b_ih[4096 + 1024 + u] + b_hh[4096 + 1024 + u];
            bi2 = b_ih[4096 + 2048 + u] + b_hh[4096 + 2048 + u];
            bi3 = b_ih[4096 + 3072 + u] + b_hh[4096 + 3072 + u];
        }
    }

    for (int k = 0; k <= 64; ++k) {
        if (!isL1) {
            if (k < 64) {
                const int t = k;
                const float* hp = (t == 0) ? h_init : (h0buf + (size_t)((t - 1) & 1) * 1024);
                float4 h0v = *(const float4*)(hp + 8 * lane);
                float4 h1v = *(const float4*)(hp + 8 * lane + 4);
                float4 h2v = *(const float4*)(hp + 512 + 8 * lane);
                float4 h3v = *(const float4*)(hp + 512 + 8 * lane + 4);
                float g[4];
                #pragma unroll
                for (int q = 0; q < 4; ++q) {
                    const uint32_t* wr = wbase + q * 512;
                    uint4 wp = *(const uint4*)(wr + lane * 4);
                    float acc = 0.f;
                    acc = fmaf(blo(wp.x), h0v.x, acc); acc = fmaf(bhi(wp.x), h0v.y, acc);
                    acc = fmaf(blo(wp.y), h0v.z, acc); acc = fmaf(bhi(wp.y), h0v.w, acc);
                    acc = fmaf(blo(wp.z), h1v.x, acc); acc = fmaf(bhi(wp.z), h1v.y, acc);
                    acc = fmaf(blo(wp.w), h1v.z, acc); acc = fmaf(bhi(wp.w), h1v.w, acc);
                    wp = *(const uint4*)(wr + 256 + lane * 4);
                    acc = fmaf(blo(wp.x), h2v.x, acc); acc = fmaf(bhi(wp.x), h2v.y, acc);
                    acc = fmaf(blo(wp.y), h2v.z, acc); acc = fmaf(bhi(wp.y), h2v.w, acc);
                    acc = fmaf(blo(wp.z), h3v.x, acc); acc = fmaf(bhi(wp.z), h3v.y, acc);
                    acc = fmaf(blo(wp.w), h3v.z, acc); acc = fmaf(bhi(wp.w), h3v.w, acc);
                    #pragma unroll
                    for (int m = 32; m; m >>= 1) acc += __shfl_xor(acc, m, 64);
                    g[q] = acc;
                }
                if (lane == 0) {
                    const float* gin = Gin0 + (size_t)t * 4096;
                    float gi = g[0] + gin[u];
                    float gf = g[1] + gin[1024 + u];
                    float gg = g[2] + gin[2048 + u];
                    float go = g[3] + gin[3072 + u];
                    float c = sigf_(gf) * cst + sigf_(gi) * tanhf(gg);
                    float hn = sigf_(go) * tanhf(c);
                    cst = c;
                    __hip_atomic_store(h0buf + (size_t)(t & 1) * 1024 + u, hn,
                                       __ATOMIC_RELAXED, __HIP_MEMORY_SCOPE_AGENT);
                    if (t == 63) out_ht[u] = hn;
                    __threadfence();
                }
            }
        } else {
            if (k >= 1) {
                const int t = k - 1;
                const float* xp = h0buf + (size_t)(t & 1) * 1024;   // h0[t]
                const float* hp = (t == 0) ? (h_init + 1024)
                                           : (h1buf + (size_t)((t - 1) & 1) * 1024);
                float4 x0v = *(const float4*)(xp + 8 * lane);
                float4 x1v = *(const float4*)(xp + 8 * lane + 4);
                float4 x2v = *(const float4*)(xp + 512 + 8 * lane);
                float4 x3v = *(const float4*)(xp + 512 + 8 * lane + 4);
                float4 h0v = *(const float4*)(hp + 8 * lane);
                float4 h1v = *(const float4*)(hp + 8 * lane + 4);
                float4 h2v = *(const float4*)(hp + 512 + 8 * lane);
                float4 h3v = *(const float4*)(hp + 512 + 8 * lane + 4);
                float g[4];
                #pragma unroll
                for (int q = 0; q < 4; ++q) {
                    const uint32_t* wr = wbase + q * 1024;
                    uint4 wp = *(const uint4*)(wr + lane * 4);
                    float acc = 0.f;
                    acc = fmaf(blo(wp.x), x0v.x, acc); acc = fmaf(bhi(wp.x), x0v.y, acc);
                    acc = fmaf(blo(wp.y), x0v.z, acc); acc = fmaf(bhi(wp.y), x0v.w, acc);
                    acc = fmaf(blo(wp.z), x1v.x, acc); acc = fmaf(bhi(wp.z), x1v.y, acc);
                    acc = fmaf(blo(wp.w), x1v.z, acc); acc = fmaf(bhi(wp.w), x1v.w, acc);
                    wp = *(const uint4*)(wr + 256 + lane * 4);
                    acc = fmaf(blo(wp.x), x2v.x, acc); acc = fmaf(bhi(wp.x), x2v.y, acc);
                    acc = fmaf(blo(wp.y), x2v.z, acc); acc = fmaf(bhi(wp.y), x2v.w, acc);
                    acc = fmaf(blo(wp.z), x3v.x, acc); acc = fmaf(bhi(wp.z), x3v.y, acc);
                    acc = fmaf(blo(wp.w), x3v.z, acc); acc = fmaf(bhi(wp.w), x3v.w, acc);
                    wp = *(const uint4*)(wr + 512 + lane * 4);
                    acc = fmaf(blo(wp.x), h0v.x, acc); acc = fmaf(bhi(wp.x), h0v.y, acc);
                    acc = fmaf(blo(wp.y), h0v.z, acc); acc = fmaf(bhi(wp.y), h0v.w, acc);
                    acc = fmaf(blo(wp.z), h1v.x, acc); acc = fmaf(bhi(wp.z), h1v.y, acc);
                    acc = fmaf(blo(wp.w), h1v.z, acc); acc = fmaf(bhi(wp.w), h1v.w, acc);
                    wp = *(const uint4*)(wr + 768 + lane * 4);
                    acc = fmaf(blo(wp.x), h2v.x, acc); acc = fmaf(bhi(wp.x), h2v.y, acc);
                    acc = fmaf(blo(wp.y), h2v.z, acc); acc = fmaf(bhi(wp.y), h2v.w, acc);
                    acc = fmaf(blo(wp.z), h3v.x, acc); acc = fmaf(bhi(wp.z), h3v.y, acc);
                    acc = fmaf(blo(wp.w), h3v.z, acc); acc = fmaf(bhi(wp.w), h3v.w, acc);
                    #pragma unroll
                    for (int m = 32; m; m >>= 1) acc += __shfl_xor(acc, m, 64);
                    g[q] = acc;
                }
                if (lane == 0) {
                    float gi = g[0] + bi0, gf = g[1] + bi1, gg = g[2] + bi2, go = g[3] + bi3;
                    float c = sigf_(gf) * cst + sigf_(gi) * tanhf(gg);
                    float hn = sigf_(go) * tanhf(c);
                    cst = c;
                    __hip_atomic_store(h1buf + (size_t)(t & 1) * 1024 + u, hn,
                                       __ATOMIC_RELAXED, __HIP_MEMORY_SCOPE_AGENT);
                    attn[(size_t)t * 2048 + u] = hn;
                    outs_bf[(size_t)t * 1024 + u] = f2bf(hn);
                    if (t == 63) out_ht[1024 + u] = hn;
                    __threadfence();
                }
            }
        }
        // ---- grid barrier between stages ----
        if (k < 64) {
            __syncthreads();
            if (tid == 0) {
                unsigned prev = __hip_atomic_fetch_add(bar + k, 1u,
                                    __ATOMIC_ACQ_REL, __HIP_MEMORY_SCOPE_AGENT);
                if (prev == RB - 1) {
                    __hip_atomic_store(bar + 72, (unsigned)(k + 1),
                                       __ATOMIC_RELEASE, __HIP_MEMORY_SCOPE_AGENT);
                } else {
                    while (__hip_atomic_load(bar + 72, __ATOMIC_ACQUIRE,
                                             __HIP_MEMORY_SCOPE_AGENT) < (unsigned)(k + 1))
                        __builtin_amdgcn_s_sleep(2);
                }
            }
            __syncthreads();
        }
    }
    if (lane == 0) out_ct[(isL1 ? 1024 : 0) + u] = cst;
}

// ---------------------------------------------------------------------------
// Attention (unchanged from round 1 — correct, small)
// ---------------------------------------------------------------------------
__global__ __launch_bounds__(256) void k_attn(
    const float* __restrict__ enc, float* __restrict__ attn)
{
    __shared__ __align__(16) float os[1024];
    __shared__ float ss[64];
    __shared__ float ws[64];
    const int t = blockIdx.x;
    const int tid = threadIdx.x;
    const float* orow = attn + (size_t)t * 2048;
    for (int i = tid; i < 1024; i += 256) os[i] = orow[i];
    __syncthreads();
    const int wave = tid >> 6, lane = tid & 63;
    for (int li = 0; li < 16; ++li) {
        const int l = wave * 16 + li;
        const float4* er = (const float4*)(enc + (size_t)l * 1024);
        float acc = 0.f;
        #pragma unroll
        for (int it = 0; it < 4; ++it) {
            float4 e4 = er[lane + 64 * it];
            float4 o4 = ((const float4*)os)[lane + 64 * it];
            acc = fmaf(e4.x, o4.x, fmaf(e4.y, o4.y, fmaf(e4.z, o4.z, fmaf(e4.w, o4.w, acc))));
        }
        #pragma unroll
        for (int off = 32; off; off >>= 1) acc += __shfl_xor(acc, off, 64);
        if (lane == 0) ss[l] = acc;
    }
    __syncthreads();
    if (tid < 64) {
        float v = ss[tid];
        float mx = v;
        #pragma unroll
        for (int off = 32; off; off >>= 1) mx = fmaxf(mx, __shfl_xor(mx, off, 64));
        float e = expf(v - mx);
        float sum = e;
        #pragma unroll
        for (int off = 32; off; off >>= 1) sum += __shfl_xor(sum, off, 64);
        ws[tid] = e / sum;
    }
    __syncthreads();
    #pragma unroll
    for (int c = 0; c < 4; ++c) {
        const int col = tid + c * 256;
        float acc = 0.f;
        for (int l = 0; l < 64; ++l) acc = fmaf(ws[l], enc[(size_t)l * 1024 + col], acc);
        attn[(size_t)t * 2048 + 1024 + col] = acc;
    }
}

// ---------------------------------------------------------------------------
extern "C" void kernel_launch(void* const* d_in, const int* in_sizes, int n_in,
                              void* d_out, int out_size, void* d_ws, size_t ws_size,
                              hipStream_t stream)
{
    const float* dec  = (const float*)d_in[0];
    const float* z    = (const float*)d_in[1];
    const float* enc  = (const float*)d_in[2];
    const float* h0   = (const float*)d_in[3];
    const float* c0   = (const float*)d_in[4];
    const float* W_ih = (const float*)d_in[5];
    const float* W_hh = (const float*)d_in[6];
    const float* b_ih = (const float*)d_in[7];
    const float* b_hh = (const float*)d_in[8];
    const float* W_fc = (const float*)d_in[9];
    const float* b_fc = (const float*)d_in[10];

    float* out    = (float*)d_out;
    float* logits = out + OUT_LOGITS;
    float* attn   = out + OUT_ATTN;
    float* out_ht = out + OUT_HT;
    float* out_ct = out + OUT_CT;

    char* wsb = (char*)d_ws;
    unsigned* bar          = (unsigned*)wsb;                      // 512 B (cnt[0..64], gen@72)
    float* Gin0            = (float*)(wsb + 512);                 // 64*4096 f = 1 MB
    float* h0buf           = Gin0 + 64 * 4096;                    // 2*1024 f
    float* h1buf           = h0buf + 2048;                        // 2*1024 f
    unsigned short* Xbf    = (unsigned short*)(h1buf + 2048);     // 64*1024 bf16
    unsigned short* outs_bf = Xbf + 65536;                        // 64*1024 bf16

    hipMemsetAsync(bar, 0, 512, stream);
    k_prep_x<<<256, 256, 0, stream>>>(dec, z, Xbf);
    k_gemm<<<64, 256, 0, stream>>>(W_ih, Xbf, b_ih, b_hh, Gin0, 4096);

    const float* a0 = W_ih; const float* a1 = W_hh; const float* a2 = b_ih;
    const float* a3 = b_hh; const float* a4 = h0;   const float* a5 = c0;
    const float* a6 = Gin0; float* a7 = h0buf; float* a8 = h1buf;
    unsigned* a9 = bar; float* a10 = attn; unsigned short* a11 = outs_bf;
    float* a12 = out_ht; float* a13 = out_ct;
    void* kargs[] = {&a0, &a1, &a2, &a3, &a4, &a5, &a6, &a7, &a8, &a9, &a10, &a11, &a12, &a13};
    hipLaunchCooperativeKernel((const void*)k_recur, dim3(RB), dim3(256), kargs, 0, stream);

    k_attn<<<64, 256, 0, stream>>>(enc, attn);
    k_gemm<<<500, 256, 0, stream>>>(W_fc, outs_bf, b_fc, nullptr, logits, 32000);
}

// Round 3
// 1111.573 us; speedup vs baseline: 3.3500x; 3.3500x over previous
//
#include <hip/hip_runtime.h>
#include <cstdint>
#include <cstddef>

// B=1, S=64, L_ENC=64, E=512, Z=512, H=1024, NL=2, V=32000
// Outputs flat: logits [64][32000], attn_out [64][2048], hT [2][1024], cT [2][1024]

#define OUT_LOGITS 0
#define OUT_ATTN   2048000
#define OUT_HT     (2048000+131072)
#define OUT_CT     (OUT_HT+2048)
#define RB 512   // blocks in the persistent recurrence kernel

typedef short short8v __attribute__((ext_vector_type(8)));
typedef float floatx4 __attribute__((ext_vector_type(4)));

__device__ __forceinline__ float sigf_(float x) { return 1.0f / (1.0f + expf(-x)); }
__device__ __forceinline__ unsigned short f2bf(float x) {
    unsigned u = __float_as_uint(x);
    return (unsigned short)((u + 0x7fffu + ((u >> 16) & 1u)) >> 16);   // RNE
}
__device__ __forceinline__ unsigned pk2(float lo, float hi) {
    return (unsigned)f2bf(lo) | ((unsigned)f2bf(hi) << 16);
}
__device__ __forceinline__ float blo(unsigned u) { return __uint_as_float(u << 16); }
__device__ __forceinline__ float bhi(unsigned u) { return __uint_as_float(u & 0xffff0000u); }

// ---------------------------------------------------------------------------
__global__ __launch_bounds__(256) void k_prep_x(
    const float* __restrict__ dec, const float* __restrict__ z,
    unsigned short* __restrict__ Xbf)
{
    int i = blockIdx.x * 256 + threadIdx.x;      // grid 256 -> 65536
    int t = i >> 10, k = i & 1023;
    float v = (k < 512) ? dec[t * 512 + k] : z[k - 512];
    Xbf[i] = f2bf(v);
}

// ---------------------------------------------------------------------------
// MFMA GEMM: out[t][m] = sum_k A[m][k]*B[t][k] + bias1[m] (+bias2[m])
// A fp32 [M][1024] converted to bf16 in-flight, B bf16 [64][1024].
// Block = 4 waves, each wave 16 m x 64 t. Grid = M/64.
// ---------------------------------------------------------------------------
__global__ __launch_bounds__(256) void k_gemm(
    const float* __restrict__ A, const unsigned short* __restrict__ Bb,
    const float* __restrict__ bias1, const float* __restrict__ bias2,
    float* __restrict__ out, int M)
{
    const int tid = threadIdx.x, wave = tid >> 6, lane = tid & 63;
    const int m0 = blockIdx.x * 64 + wave * 16;
    const int mr = lane & 15, kq = lane >> 4;
    const float* arow = A + (size_t)(m0 + mr) * 1024 + kq * 8;
    const unsigned short* brow = Bb + (size_t)mr * 1024 + kq * 8;
    floatx4 acc[4] = {};

    for (int kk = 0; kk < 1024; kk += 32) {
        float4 a0 = *(const float4*)(arow + kk);
        float4 a1 = *(const float4*)(arow + kk + 4);
        short8v af;
        af[0] = (short)f2bf(a0.x); af[1] = (short)f2bf(a0.y);
        af[2] = (short)f2bf(a0.z); af[3] = (short)f2bf(a0.w);
        af[4] = (short)f2bf(a1.x); af[5] = (short)f2bf(a1.y);
        af[6] = (short)f2bf(a1.z); af[7] = (short)f2bf(a1.w);
        #pragma unroll
        for (int g = 0; g < 4; ++g) {
            short8v bf = *(const short8v*)(brow + (size_t)g * 16 * 1024 + kk);
            acc[g] = __builtin_amdgcn_mfma_f32_16x16x32_bf16(af, bf, acc[g], 0, 0, 0);
        }
    }
    const int mo = m0 + (kq << 2);
    float4 bv = *(const float4*)(bias1 + mo);
    if (bias2) {
        float4 b2 = *(const float4*)(bias2 + mo);
        bv.x += b2.x; bv.y += b2.y; bv.z += b2.z; bv.w += b2.w;
    }
    #pragma unroll
    for (int g = 0; g < 4; ++g) {
        const int t = g * 16 + mr;
        float4 o;
        o.x = acc[g][0] + bv.x; o.y = acc[g][1] + bv.y;
        o.z = acc[g][2] + bv.z; o.w = acc[g][3] + bv.w;
        *(float4*)(out + (size_t)t * M + mo) = o;
    }
}

// ---------------------------------------------------------------------------
// Persistent recurrence. 512 blocks x 256 thr, weights LDS-resident (bf16).
// Cross-block data ONLY via relaxed agent atomics (sc1 -> L3 coherence point);
// barrier = waitcnt vmcnt(0) + relaxed fetch_add on 8 spread cachelines +
// relaxed poll-sum. NO acquire/release fences -> no buffer_inv/wbl2 storms.
// ---------------------------------------------------------------------------
__global__ __launch_bounds__(256, 2) void k_recur(
    const float* __restrict__ W_ih, const float* __restrict__ W_hh,
    const float* __restrict__ b_ih, const float* __restrict__ b_hh,
    const float* __restrict__ h_init, const float* __restrict__ c_init,
    const float* __restrict__ Gin0,
    float* __restrict__ h0buf,   // [2][1024] ping-pong (L3-coherent traffic)
    float* __restrict__ h1buf,   // [2][1024]
    unsigned* __restrict__ bar,  // 8 counters, 64B apart
    float* __restrict__ attn,
    unsigned short* __restrict__ outs_bf,
    float* __restrict__ out_ht, float* __restrict__ out_ct)
{
    __shared__ uint32_t wls[8 * 512 + 8 * 1024];   // 48 KB packed bf16 weights
    __shared__ float hs0[1024];                    // h0[k-1]
    __shared__ float hs1[1024];                    // h1[k-2]
    const int tid = threadIdx.x, wave = tid >> 6, lane = tid & 63;
    const bool isL1 = wave >= 2;
    const int u = blockIdx.x * 2 + (wave & 1);
    uint32_t* wbase = isL1 ? (wls + 8 * 512 + (wave & 1) * 4 * 1024)
                           : (wls + (wave & 1) * 4 * 512);

    // ---- stage weights into LDS as packed bf16 ----
    if (!isL1) {
        #pragma unroll
        for (int q = 0; q < 4; ++q) {
            const float* row = W_hh + (size_t)(q * 1024 + u) * 1024;
            uint32_t* dst = wbase + q * 512;
            #pragma unroll
            for (int jq = 0; jq < 2; ++jq) {
                float4 a = *(const float4*)(row + 512 * jq + 8 * lane);
                float4 b = *(const float4*)(row + 512 * jq + 8 * lane + 4);
                uint4 p;
                p.x = pk2(a.x, a.y); p.y = pk2(a.z, a.w);
                p.z = pk2(b.x, b.y); p.w = pk2(b.z, b.w);
                *(uint4*)(dst + jq * 256 + lane * 4) = p;
            }
        }
    } else {
        #pragma unroll
        for (int q = 0; q < 4; ++q) {
            const float* rowi = W_ih + (size_t)4096 * 1024 + (size_t)(q * 1024 + u) * 1024;
            const float* rowh = W_hh + (size_t)4096 * 1024 + (size_t)(q * 1024 + u) * 1024;
            uint32_t* dst = wbase + q * 1024;
            #pragma unroll
            for (int jq = 0; jq < 2; ++jq) {
                float4 a = *(const float4*)(rowi + 512 * jq + 8 * lane);
                float4 b = *(const float4*)(rowi + 512 * jq + 8 * lane + 4);
                uint4 p;
                p.x = pk2(a.x, a.y); p.y = pk2(a.z, a.w);
                p.z = pk2(b.x, b.y); p.w = pk2(b.z, b.w);
                *(uint4*)(dst + jq * 256 + lane * 4) = p;
                a = *(const float4*)(rowh + 512 * jq + 8 * lane);
                b = *(const float4*)(rowh + 512 * jq + 8 * lane + 4);
                p.x = pk2(a.x, a.y); p.y = pk2(a.z, a.w);
                p.z = pk2(b.x, b.y); p.w = pk2(b.z, b.w);
                *(uint4*)(dst + 512 + jq * 256 + lane * 4) = p;
            }
        }
    }

    float cst = 0.f, bi0 = 0.f, bi1 = 0.f, bi2 = 0.f, bi3 = 0.f;
    if (lane == 0) {
        cst = c_init[(isL1 ? 1024 : 0) + u];
        if (isL1) {
            bi0 = b_ih[4096 + u]        + b_hh[4096 + u];
            bi1 = b_ih[4096 + 1024 + u] + b_hh[4096 + 1024 + u];
            bi2 = b_ih[4096 + 2048 + u] + b_hh[4096 + 2048 + u];
            bi3 = b_ih[4096 + 3072 + u] + b_hh[4096 + 3072 + u];
        }
    }
    __syncthreads();

    for (int k = 0; k <= 64; ++k) {
        // ---- stage h vectors into LDS via sc1 (L3-coherent) loads ----
        {
            const float* s0 = (k == 0) ? h_init : (h0buf + (size_t)((k - 1) & 1) * 1024);
            #pragma unroll
            for (int j = 0; j < 4; ++j) {
                int i = tid + j * 256;
                hs0[i] = __hip_atomic_load(s0 + i, __ATOMIC_RELAXED, __HIP_MEMORY_SCOPE_AGENT);
            }
            if (k >= 1) {
                const float* s1 = (k == 1) ? (h_init + 1024)
                                           : (h1buf + (size_t)(k & 1) * 1024);  // (k-2)&1 == k&1
                #pragma unroll
                for (int j = 0; j < 4; ++j) {
                    int i = tid + j * 256;
                    hs1[i] = __hip_atomic_load(s1 + i, __ATOMIC_RELAXED, __HIP_MEMORY_SCOPE_AGENT);
                }
            }
        }
        __syncthreads();

        if (!isL1) {
            if (k < 64) {
                const int t = k;
                float4 h0v = ((const float4*)hs0)[2 * lane];
                float4 h1v = ((const float4*)hs0)[2 * lane + 1];
                float4 h2v = ((const float4*)hs0)[128 + 2 * lane];
                float4 h3v = ((const float4*)hs0)[128 + 2 * lane + 1];
                float g[4];
                #pragma unroll
                for (int q = 0; q < 4; ++q) {
                    const uint32_t* wr = wbase + q * 512;
                    uint4 wp = *(const uint4*)(wr + lane * 4);
                    float acc = 0.f;
                    acc = fmaf(blo(wp.x), h0v.x, acc); acc = fmaf(bhi(wp.x), h0v.y, acc);
                    acc = fmaf(blo(wp.y), h0v.z, acc); acc = fmaf(bhi(wp.y), h0v.w, acc);
                    acc = fmaf(blo(wp.z), h1v.x, acc); acc = fmaf(bhi(wp.z), h1v.y, acc);
                    acc = fmaf(blo(wp.w), h1v.z, acc); acc = fmaf(bhi(wp.w), h1v.w, acc);
                    wp = *(const uint4*)(wr + 256 + lane * 4);
                    acc = fmaf(blo(wp.x), h2v.x, acc); acc = fmaf(bhi(wp.x), h2v.y, acc);
                    acc = fmaf(blo(wp.y), h2v.z, acc); acc = fmaf(bhi(wp.y), h2v.w, acc);
                    acc = fmaf(blo(wp.z), h3v.x, acc); acc = fmaf(bhi(wp.z), h3v.y, acc);
                    acc = fmaf(blo(wp.w), h3v.z, acc); acc = fmaf(bhi(wp.w), h3v.w, acc);
                    #pragma unroll
                    for (int m = 32; m; m >>= 1) acc += __shfl_xor(acc, m, 64);
                    g[q] = acc;
                }
                if (lane == 0) {
                    const float* gin = Gin0 + (size_t)t * 4096;
                    float gi = g[0] + gin[u];
                    float gf = g[1] + gin[1024 + u];
                    float gg = g[2] + gin[2048 + u];
                    float go = g[3] + gin[3072 + u];
                    float c = sigf_(gf) * cst + sigf_(gi) * tanhf(gg);
                    float hn = sigf_(go) * tanhf(c);
                    cst = c;
                    __hip_atomic_store(h0buf + (size_t)(t & 1) * 1024 + u, hn,
                                       __ATOMIC_RELAXED, __HIP_MEMORY_SCOPE_AGENT);
                    if (t == 63) out_ht[u] = hn;
                }
            }
        } else {
            if (k >= 1) {
                const int t = k - 1;
                float4 x0v = ((const float4*)hs0)[2 * lane];
                float4 x1v = ((const float4*)hs0)[2 * lane + 1];
                float4 x2v = ((const float4*)hs0)[128 + 2 * lane];
                float4 x3v = ((const float4*)hs0)[128 + 2 * lane + 1];
                float4 h0v = ((const float4*)hs1)[2 * lane];
                float4 h1v = ((const float4*)hs1)[2 * lane + 1];
                float4 h2v = ((const float4*)hs1)[128 + 2 * lane];
                float4 h3v = ((const float4*)hs1)[128 + 2 * lane + 1];
                float g[4];
                #pragma unroll
                for (int q = 0; q < 4; ++q) {
                    const uint32_t* wr = wbase + q * 1024;
                    uint4 wp = *(const uint4*)(wr + lane * 4);
                    float acc = 0.f;
                    acc = fmaf(blo(wp.x), x0v.x, acc); acc = fmaf(bhi(wp.x), x0v.y, acc);
                    acc = fmaf(blo(wp.y), x0v.z, acc); acc = fmaf(bhi(wp.y), x0v.w, acc);
                    acc = fmaf(blo(wp.z), x1v.x, acc); acc = fmaf(bhi(wp.z), x1v.y, acc);
                    acc = fmaf(blo(wp.w), x1v.z, acc); acc = fmaf(bhi(wp.w), x1v.w, acc);
                    wp = *(const uint4*)(wr + 256 + lane * 4);
                    acc = fmaf(blo(wp.x), x2v.x, acc); acc = fmaf(bhi(wp.x), x2v.y, acc);
                    acc = fmaf(blo(wp.y), x2v.z, acc); acc = fmaf(bhi(wp.y), x2v.w, acc);
                    acc = fmaf(blo(wp.z), x3v.x, acc); acc = fmaf(bhi(wp.z), x3v.y, acc);
                    acc = fmaf(blo(wp.w), x3v.z, acc); acc = fmaf(bhi(wp.w), x3v.w, acc);
                    wp = *(const uint4*)(wr + 512 + lane * 4);
                    acc = fmaf(blo(wp.x), h0v.x, acc); acc = fmaf(bhi(wp.x), h0v.y, acc);
                    acc = fmaf(blo(wp.y), h0v.z, acc); acc = fmaf(bhi(wp.y), h0v.w, acc);
                    acc = fmaf(blo(wp.z), h1v.x, acc); acc = fmaf(bhi(wp.z), h1v.y, acc);
                    acc = fmaf(blo(wp.w), h1v.z, acc); acc = fmaf(bhi(wp.w), h1v.w, acc);
                    wp = *(const uint4*)(wr + 768 + lane * 4);
                    acc = fmaf(blo(wp.x), h2v.x, acc); acc = fmaf(bhi(wp.x), h2v.y, acc);
                    acc = fmaf(blo(wp.y), h2v.z, acc); acc = fmaf(bhi(wp.y), h2v.w, acc);
                    acc = fmaf(blo(wp.z), h3v.x, acc); acc = fmaf(bhi(wp.z), h3v.y, acc);
                    acc = fmaf(blo(wp.w), h3v.z, acc); acc = fmaf(bhi(wp.w), h3v.w, acc);
                    #pragma unroll
                    for (int m = 32; m; m >>= 1) acc += __shfl_xor(acc, m, 64);
                    g[q] = acc;
                }
                if (lane == 0) {
                    float gi = g[0] + bi0, gf = g[1] + bi1, gg = g[2] + bi2, go = g[3] + bi3;
                    float c = sigf_(gf) * cst + sigf_(gi) * tanhf(gg);
                    float hn = sigf_(go) * tanhf(c);
                    cst = c;
                    __hip_atomic_store(h1buf + (size_t)(t & 1) * 1024 + u, hn,
                                       __ATOMIC_RELAXED, __HIP_MEMORY_SCOPE_AGENT);
                    attn[(size_t)t * 2048 + u] = hn;
                    outs_bf[(size_t)t * 1024 + u] = f2bf(hn);
                    if (t == 63) out_ht[1024 + u] = hn;
                }
            }
        }

        // ---- zero-cache-op grid barrier ----
        if (k < 64) {
            asm volatile("s_waitcnt vmcnt(0)" ::: "memory");  // h stores drained to L3
            __syncthreads();
            if (tid == 0) {
                __hip_atomic_fetch_add(bar + (blockIdx.x & 7) * 16, 1u,
                                       __ATOMIC_RELAXED, __HIP_MEMORY_SCOPE_AGENT);
                const unsigned target = (unsigned)(k + 1) * RB;
                for (;;) {
                    unsigned s = 0;
                    #pragma unroll
                    for (int g = 0; g < 8; ++g)
                        s += __hip_atomic_load(bar + g * 16, __ATOMIC_RELAXED,
                                               __HIP_MEMORY_SCOPE_AGENT);
                    if (s >= target) break;
                    __builtin_amdgcn_s_sleep(2);
                }
            }
            asm volatile("" ::: "memory");
            __syncthreads();
        }
    }
    if (lane == 0) out_ct[(isL1 ? 1024 : 0) + u] = cst;
}

// ---------------------------------------------------------------------------
__global__ __launch_bounds__(256) void k_attn(
    const float* __restrict__ enc, float* __restrict__ attn)
{
    __shared__ __align__(16) float os[1024];
    __shared__ float ss[64];
    __shared__ float ws[64];
    const int t = blockIdx.x;
    const int tid = threadIdx.x;
    const float* orow = attn + (size_t)t * 2048;
    for (int i = tid; i < 1024; i += 256) os[i] = orow[i];
    __syncthreads();
    const int wave = tid >> 6, lane = tid & 63;
    for (int li = 0; li < 16; ++li) {
        const int l = wave * 16 + li;
        const float4* er = (const float4*)(enc + (size_t)l * 1024);
        float acc = 0.f;
        #pragma unroll
        for (int it = 0; it < 4; ++it) {
            float4 e4 = er[lane + 64 * it];
            float4 o4 = ((const float4*)os)[lane + 64 * it];
            acc = fmaf(e4.x, o4.x, fmaf(e4.y, o4.y, fmaf(e4.z, o4.z, fmaf(e4.w, o4.w, acc))));
        }
        #pragma unroll
        for (int off = 32; off; off >>= 1) acc += __shfl_xor(acc, off, 64);
        if (lane == 0) ss[l] = acc;
    }
    __syncthreads();
    if (tid < 64) {
        float v = ss[tid];
        float mx = v;
        #pragma unroll
        for (int off = 32; off; off >>= 1) mx = fmaxf(mx, __shfl_xor(mx, off, 64));
        float e = expf(v - mx);
        float sum = e;
        #pragma unroll
        for (int off = 32; off; off >>= 1) sum += __shfl_xor(sum, off, 64);
        ws[tid] = e / sum;
    }
    __syncthreads();
    #pragma unroll
    for (int c = 0; c < 4; ++c) {
        const int col = tid + c * 256;
        float acc = 0.f;
        for (int l = 0; l < 64; ++l) acc = fmaf(ws[l], enc[(size_t)l * 1024 + col], acc);
        attn[(size_t)t * 2048 + 1024 + col] = acc;
    }
}

// ---------------------------------------------------------------------------
extern "C" void kernel_launch(void* const* d_in, const int* in_sizes, int n_in,
                              void* d_out, int out_size, void* d_ws, size_t ws_size,
                              hipStream_t stream)
{
    const float* dec  = (const float*)d_in[0];
    const float* z    = (const float*)d_in[1];
    const float* enc  = (const float*)d_in[2];
    const float* h0   = (const float*)d_in[3];
    const float* c0   = (const float*)d_in[4];
    const float* W_ih = (const float*)d_in[5];
    const float* W_hh = (const float*)d_in[6];
    const float* b_ih = (const float*)d_in[7];
    const float* b_hh = (const float*)d_in[8];
    const float* W_fc = (const float*)d_in[9];
    const float* b_fc = (const float*)d_in[10];

    float* out    = (float*)d_out;
    float* logits = out + OUT_LOGITS;
    float* attn   = out + OUT_ATTN;
    float* out_ht = out + OUT_HT;
    float* out_ct = out + OUT_CT;

    char* wsb = (char*)d_ws;
    unsigned* bar          = (unsigned*)wsb;                      // 8 counters, 64B apart
    float* Gin0            = (float*)(wsb + 512);
    float* h0buf           = Gin0 + 64 * 4096;
    float* h1buf           = h0buf + 2048;
    unsigned short* Xbf    = (unsigned short*)(h1buf + 2048);
    unsigned short* outs_bf = Xbf + 65536;

    hipMemsetAsync(bar, 0, 512, stream);
    k_prep_x<<<256, 256, 0, stream>>>(dec, z, Xbf);
    k_gemm<<<64, 256, 0, stream>>>(W_ih, Xbf, b_ih, b_hh, Gin0, 4096);

    const float* a0 = W_ih; const float* a1 = W_hh; const float* a2 = b_ih;
    const float* a3 = b_hh; const float* a4 = h0;   const float* a5 = c0;
    const float* a6 = Gin0; float* a7 = h0buf; float* a8 = h1buf;
    unsigned* a9 = bar; float* a10 = attn; unsigned short* a11 = outs_bf;
    float* a12 = out_ht; float* a13 = out_ct;
    void* kargs[] = {&a0, &a1, &a2, &a3, &a4, &a5, &a6, &a7, &a8, &a9, &a10, &a11, &a12, &a13};
    hipLaunchCooperativeKernel((const void*)k_recur, dim3(RB), dim3(256), kargs, 0, stream);

    k_attn<<<64, 256, 0, stream>>>(enc, attn);
    k_gemm<<<500, 256, 0, stream>>>(W_fc, outs_bf, b_fc, nullptr, logits, 32000);
}

// Round 4
// 709.852 us; speedup vs baseline: 5.2458x; 1.5659x over previous
//
#include <hip/hip_runtime.h>
#include <cstdint>
#include <cstddef>

// B=1, S=64, L_ENC=64, E=512, Z=512, H=1024, NL=2, V=32000
// Outputs flat: logits [64][32000], attn_out [64][2048], hT [2][1024], cT [2][1024]

#define OUT_LOGITS 0
#define OUT_ATTN   2048000
#define OUT_HT     (2048000+131072)
#define OUT_CT     (OUT_HT+2048)
#define RB 512   // blocks in the persistent recurrence kernel

typedef short short8v __attribute__((ext_vector_type(8)));
typedef float floatx4 __attribute__((ext_vector_type(4)));

__device__ __forceinline__ float sigf_(float x) { return 1.0f / (1.0f + expf(-x)); }
__device__ __forceinline__ unsigned short f2bf(float x) {
    unsigned u = __float_as_uint(x);
    return (unsigned short)((u + 0x7fffu + ((u >> 16) & 1u)) >> 16);   // RNE
}
__device__ __forceinline__ unsigned pk2(float lo, float hi) {
    return (unsigned)f2bf(lo) | ((unsigned)f2bf(hi) << 16);
}
__device__ __forceinline__ float blo(unsigned u) { return __uint_as_float(u << 16); }
__device__ __forceinline__ float bhi(unsigned u) { return __uint_as_float(u & 0xffff0000u); }

// ---------------------------------------------------------------------------
__global__ __launch_bounds__(256) void k_prep_x(
    const float* __restrict__ dec, const float* __restrict__ z,
    unsigned short* __restrict__ Xbf)
{
    int i = blockIdx.x * 256 + threadIdx.x;      // grid 256 -> 65536
    int t = i >> 10, k = i & 1023;
    float v = (k < 512) ? dec[t * 512 + k] : z[k - 512];
    Xbf[i] = f2bf(v);
}

// ---------------------------------------------------------------------------
// MFMA GEMM: out[t][m] = sum_k A[m][k]*B[t][k] + bias1[m] (+bias2[m])
// A fp32 [M][1024] converted to bf16 in-flight, B bf16 [64][1024].
// Block = 4 waves, each wave 16 m x 64 t. Grid = M/64.
// ---------------------------------------------------------------------------
__global__ __launch_bounds__(256) void k_gemm(
    const float* __restrict__ A, const unsigned short* __restrict__ Bb,
    const float* __restrict__ bias1, const float* __restrict__ bias2,
    float* __restrict__ out, int M)
{
    const int tid = threadIdx.x, wave = tid >> 6, lane = tid & 63;
    const int m0 = blockIdx.x * 64 + wave * 16;
    const int mr = lane & 15, kq = lane >> 4;
    const float* arow = A + (size_t)(m0 + mr) * 1024 + kq * 8;
    const unsigned short* brow = Bb + (size_t)mr * 1024 + kq * 8;
    floatx4 acc[4] = {};

    for (int kk = 0; kk < 1024; kk += 32) {
        float4 a0 = *(const float4*)(arow + kk);
        float4 a1 = *(const float4*)(arow + kk + 4);
        short8v af;
        af[0] = (short)f2bf(a0.x); af[1] = (short)f2bf(a0.y);
        af[2] = (short)f2bf(a0.z); af[3] = (short)f2bf(a0.w);
        af[4] = (short)f2bf(a1.x); af[5] = (short)f2bf(a1.y);
        af[6] = (short)f2bf(a1.z); af[7] = (short)f2bf(a1.w);
        #pragma unroll
        for (int g = 0; g < 4; ++g) {
            short8v bf = *(const short8v*)(brow + (size_t)g * 16 * 1024 + kk);
            acc[g] = __builtin_amdgcn_mfma_f32_16x16x32_bf16(af, bf, acc[g], 0, 0, 0);
        }
    }
    const int mo = m0 + (kq << 2);
    float4 bv = *(const float4*)(bias1 + mo);
    if (bias2) {
        float4 b2 = *(const float4*)(bias2 + mo);
        bv.x += b2.x; bv.y += b2.y; bv.z += b2.z; bv.w += b2.w;
    }
    #pragma unroll
    for (int g = 0; g < 4; ++g) {
        const int t = g * 16 + mr;
        float4 o;
        o.x = acc[g][0] + bv.x; o.y = acc[g][1] + bv.y;
        o.z = acc[g][2] + bv.z; o.w = acc[g][3] + bv.w;
        *(float4*)(out + (size_t)t * M + mo) = o;
    }
}

// ---------------------------------------------------------------------------
// Persistent recurrence. 512 blocks x 256 thr, weights LDS-resident (bf16).
// Cross-block data via relaxed agent atomics only (L3 coherence point).
// Barrier: two-level accumulating arrival tree (8 lines x 64 + master) that
// NOBODY reads, plus 8 replicated release lines that nobody RMWs. This keeps
// poll reads off the arrival lines (round-3 collapse: RMWs queued behind
// ~4096 in-flight poll reads of the same lines).
// bar dwords: [g*16] arrival (g=0..7) | [128] master | [144+g*16] release
// ---------------------------------------------------------------------------
__global__ __launch_bounds__(256, 2) void k_recur(
    const float* __restrict__ W_ih, const float* __restrict__ W_hh,
    const float* __restrict__ b_ih, const float* __restrict__ b_hh,
    const float* __restrict__ h_init, const float* __restrict__ c_init,
    const float* __restrict__ Gin0,
    float* __restrict__ h0buf,   // [2][1024] ping-pong
    float* __restrict__ h1buf,   // [2][1024]
    unsigned* __restrict__ bar,
    float* __restrict__ attn,
    unsigned short* __restrict__ outs_bf,
    float* __restrict__ out_ht, float* __restrict__ out_ct)
{
    __shared__ uint32_t wls[8 * 512 + 8 * 1024];   // 48 KB packed bf16 weights
    __shared__ __align__(16) float hs0[1024];      // h0[k-1]
    __shared__ __align__(16) float hs1[1024];      // h1[k-2]
    const int tid = threadIdx.x, wave = tid >> 6, lane = tid & 63;
    const bool isL1 = wave >= 2;
    const int u = blockIdx.x * 2 + (wave & 1);
    uint32_t* wbase = isL1 ? (wls + 8 * 512 + (wave & 1) * 4 * 1024)
                           : (wls + (wave & 1) * 4 * 512);

    // ---- stage weights into LDS as packed bf16 ----
    if (!isL1) {
        #pragma unroll
        for (int q = 0; q < 4; ++q) {
            const float* row = W_hh + (size_t)(q * 1024 + u) * 1024;
            uint32_t* dst = wbase + q * 512;
            #pragma unroll
            for (int jq = 0; jq < 2; ++jq) {
                float4 a = *(const float4*)(row + 512 * jq + 8 * lane);
                float4 b = *(const float4*)(row + 512 * jq + 8 * lane + 4);
                uint4 p;
                p.x = pk2(a.x, a.y); p.y = pk2(a.z, a.w);
                p.z = pk2(b.x, b.y); p.w = pk2(b.z, b.w);
                *(uint4*)(dst + jq * 256 + lane * 4) = p;
            }
        }
    } else {
        #pragma unroll
        for (int q = 0; q < 4; ++q) {
            const float* rowi = W_ih + (size_t)4096 * 1024 + (size_t)(q * 1024 + u) * 1024;
            const float* rowh = W_hh + (size_t)4096 * 1024 + (size_t)(q * 1024 + u) * 1024;
            uint32_t* dst = wbase + q * 1024;
            #pragma unroll
            for (int jq = 0; jq < 2; ++jq) {
                float4 a = *(const float4*)(rowi + 512 * jq + 8 * lane);
                float4 b = *(const float4*)(rowi + 512 * jq + 8 * lane + 4);
                uint4 p;
                p.x = pk2(a.x, a.y); p.y = pk2(a.z, a.w);
                p.z = pk2(b.x, b.y); p.w = pk2(b.z, b.w);
                *(uint4*)(dst + jq * 256 + lane * 4) = p;
                a = *(const float4*)(rowh + 512 * jq + 8 * lane);
                b = *(const float4*)(rowh + 512 * jq + 8 * lane + 4);
                p.x = pk2(a.x, a.y); p.y = pk2(a.z, a.w);
                p.z = pk2(b.x, b.y); p.w = pk2(b.z, b.w);
                *(uint4*)(dst + 512 + jq * 256 + lane * 4) = p;
            }
        }
    }

    float cst = 0.f, bi0 = 0.f, bi1 = 0.f, bi2 = 0.f, bi3 = 0.f;
    if (lane == 0) {
        cst = c_init[(isL1 ? 1024 : 0) + u];
        if (isL1) {
            bi0 = b_ih[4096 + u]        + b_hh[4096 + u];
            bi1 = b_ih[4096 + 1024 + u] + b_hh[4096 + 1024 + u];
            bi2 = b_ih[4096 + 2048 + u] + b_hh[4096 + 2048 + u];
            bi3 = b_ih[4096 + 3072 + u] + b_hh[4096 + 3072 + u];
        }
    }
    __syncthreads();

    for (int k = 0; k <= 64; ++k) {
        // ---- stage h vectors into LDS via packed 8-B relaxed agent loads ----
        {
            const float* s0 = (k == 0) ? h_init : (h0buf + (size_t)((k - 1) & 1) * 1024);
            #pragma unroll
            for (int j = 0; j < 2; ++j) {
                int i = tid + j * 256;   // ull index 0..511
                unsigned long long v = __hip_atomic_load(
                    (const unsigned long long*)s0 + i, __ATOMIC_RELAXED,
                    __HIP_MEMORY_SCOPE_AGENT);
                ((unsigned long long*)hs0)[i] = v;
            }
            if (k >= 1) {
                const float* s1 = (k == 1) ? (h_init + 1024)
                                           : (h1buf + (size_t)(k & 1) * 1024);  // (k-2)&1
                #pragma unroll
                for (int j = 0; j < 2; ++j) {
                    int i = tid + j * 256;
                    unsigned long long v = __hip_atomic_load(
                        (const unsigned long long*)s1 + i, __ATOMIC_RELAXED,
                        __HIP_MEMORY_SCOPE_AGENT);
                    ((unsigned long long*)hs1)[i] = v;
                }
            }
        }
        __syncthreads();

        if (!isL1) {
            if (k < 64) {
                const int t = k;
                float4 h0v = ((const float4*)hs0)[2 * lane];
                float4 h1v = ((const float4*)hs0)[2 * lane + 1];
                float4 h2v = ((const float4*)hs0)[128 + 2 * lane];
                float4 h3v = ((const float4*)hs0)[128 + 2 * lane + 1];
                float g[4];
                #pragma unroll
                for (int q = 0; q < 4; ++q) {
                    const uint32_t* wr = wbase + q * 512;
                    uint4 wp = *(const uint4*)(wr + lane * 4);
                    float acc = 0.f;
                    acc = fmaf(blo(wp.x), h0v.x, acc); acc = fmaf(bhi(wp.x), h0v.y, acc);
                    acc = fmaf(blo(wp.y), h0v.z, acc); acc = fmaf(bhi(wp.y), h0v.w, acc);
                    acc = fmaf(blo(wp.z), h1v.x, acc); acc = fmaf(bhi(wp.z), h1v.y, acc);
                    acc = fmaf(blo(wp.w), h1v.z, acc); acc = fmaf(bhi(wp.w), h1v.w, acc);
                    wp = *(const uint4*)(wr + 256 + lane * 4);
                    acc = fmaf(blo(wp.x), h2v.x, acc); acc = fmaf(bhi(wp.x), h2v.y, acc);
                    acc = fmaf(blo(wp.y), h2v.z, acc); acc = fmaf(bhi(wp.y), h2v.w, acc);
                    acc = fmaf(blo(wp.z), h3v.x, acc); acc = fmaf(bhi(wp.z), h3v.y, acc);
                    acc = fmaf(blo(wp.w), h3v.z, acc); acc = fmaf(bhi(wp.w), h3v.w, acc);
                    #pragma unroll
                    for (int m = 32; m; m >>= 1) acc += __shfl_xor(acc, m, 64);
                    g[q] = acc;
                }
                if (lane == 0) {
                    const float* gin = Gin0 + (size_t)t * 4096;
                    float gi = g[0] + gin[u];
                    float gf = g[1] + gin[1024 + u];
                    float gg = g[2] + gin[2048 + u];
                    float go = g[3] + gin[3072 + u];
                    float c = sigf_(gf) * cst + sigf_(gi) * tanhf(gg);
                    float hn = sigf_(go) * tanhf(c);
                    cst = c;
                    __hip_atomic_store(h0buf + (size_t)(t & 1) * 1024 + u, hn,
                                       __ATOMIC_RELAXED, __HIP_MEMORY_SCOPE_AGENT);
                    if (t == 63) out_ht[u] = hn;
                }
            }
        } else {
            if (k >= 1) {
                const int t = k - 1;
                float4 x0v = ((const float4*)hs0)[2 * lane];
                float4 x1v = ((const float4*)hs0)[2 * lane + 1];
                float4 x2v = ((const float4*)hs0)[128 + 2 * lane];
                float4 x3v = ((const float4*)hs0)[128 + 2 * lane + 1];
                float4 h0v = ((const float4*)hs1)[2 * lane];
                float4 h1v = ((const float4*)hs1)[2 * lane + 1];
                float4 h2v = ((const float4*)hs1)[128 + 2 * lane];
                float4 h3v = ((const float4*)hs1)[128 + 2 * lane + 1];
                float g[4];
                #pragma unroll
                for (int q = 0; q < 4; ++q) {
                    const uint32_t* wr = wbase + q * 1024;
                    uint4 wp = *(const uint4*)(wr + lane * 4);
                    float acc = 0.f;
                    acc = fmaf(blo(wp.x), x0v.x, acc); acc = fmaf(bhi(wp.x), x0v.y, acc);
                    acc = fmaf(blo(wp.y), x0v.z, acc); acc = fmaf(bhi(wp.y), x0v.w, acc);
                    acc = fmaf(blo(wp.z), x1v.x, acc); acc = fmaf(bhi(wp.z), x1v.y, acc);
                    acc = fmaf(blo(wp.w), x1v.z, acc); acc = fmaf(bhi(wp.w), x1v.w, acc);
                    wp = *(const uint4*)(wr + 256 + lane * 4);
                    acc = fmaf(blo(wp.x), x2v.x, acc); acc = fmaf(bhi(wp.x), x2v.y, acc);
                    acc = fmaf(blo(wp.y), x2v.z, acc); acc = fmaf(bhi(wp.y), x2v.w, acc);
                    acc = fmaf(blo(wp.z), x3v.x, acc); acc = fmaf(bhi(wp.z), x3v.y, acc);
                    acc = fmaf(blo(wp.w), x3v.z, acc); acc = fmaf(bhi(wp.w), x3v.w, acc);
                    wp = *(const uint4*)(wr + 512 + lane * 4);
                    acc = fmaf(blo(wp.x), h0v.x, acc); acc = fmaf(bhi(wp.x), h0v.y, acc);
                    acc = fmaf(blo(wp.y), h0v.z, acc); acc = fmaf(bhi(wp.y), h0v.w, acc);
                    acc = fmaf(blo(wp.z), h1v.x, acc); acc = fmaf(bhi(wp.z), h1v.y, acc);
                    acc = fmaf(blo(wp.w), h1v.z, acc); acc = fmaf(bhi(wp.w), h1v.w, acc);
                    wp = *(const uint4*)(wr + 768 + lane * 4);
                    acc = fmaf(blo(wp.x), h2v.x, acc); acc = fmaf(bhi(wp.x), h2v.y, acc);
                    acc = fmaf(blo(wp.y), h2v.z, acc); acc = fmaf(bhi(wp.y), h2v.w, acc);
                    acc = fmaf(blo(wp.z), h3v.x, acc); acc = fmaf(bhi(wp.z), h3v.y, acc);
                    acc = fmaf(blo(wp.w), h3v.z, acc); acc = fmaf(bhi(wp.w), h3v.w, acc);
                    #pragma unroll
                    for (int m = 32; m; m >>= 1) acc += __shfl_xor(acc, m, 64);
                    g[q] = acc;
                }
                if (lane == 0) {
                    float gi = g[0] + bi0, gf = g[1] + bi1, gg = g[2] + bi2, go = g[3] + bi3;
                    float c = sigf_(gf) * cst + sigf_(gi) * tanhf(gg);
                    float hn = sigf_(go) * tanhf(c);
                    cst = c;
                    __hip_atomic_store(h1buf + (size_t)(t & 1) * 1024 + u, hn,
                                       __ATOMIC_RELAXED, __HIP_MEMORY_SCOPE_AGENT);
                    attn[(size_t)t * 2048 + u] = hn;
                    outs_bf[(size_t)t * 1024 + u] = f2bf(hn);
                    if (t == 63) out_ht[1024 + u] = hn;
                }
            }
        }

        // ---- two-level arrival tree + replicated release lines ----
        if (k < 64) {
            asm volatile("s_waitcnt vmcnt(0)" ::: "memory");  // h stores drained to L3
            __syncthreads();
            if (tid == 0) {
                const int g = blockIdx.x & 7;
                unsigned prev = __hip_atomic_fetch_add(bar + g * 16, 1u,
                                    __ATOMIC_RELAXED, __HIP_MEMORY_SCOPE_AGENT);
                if (prev + 1 == (unsigned)(k + 1) * 64) {          // 64th arrival on this line
                    unsigned mp = __hip_atomic_fetch_add(bar + 128, 1u,
                                      __ATOMIC_RELAXED, __HIP_MEMORY_SCOPE_AGENT);
                    if (mp + 1 == (unsigned)(k + 1) * 8) {         // final line-leader
                        #pragma unroll
                        for (int r = 0; r < 8; ++r)
                            __hip_atomic_store(bar + 144 + r * 16, (unsigned)(k + 1),
                                               __ATOMIC_RELAXED, __HIP_MEMORY_SCOPE_AGENT);
                    }
                }
                while (__hip_atomic_load(bar + 144 + g * 16, __ATOMIC_RELAXED,
                                         __HIP_MEMORY_SCOPE_AGENT) < (unsigned)(k + 1))
                    __builtin_amdgcn_s_sleep(1);
            }
            asm volatile("" ::: "memory");
            __syncthreads();
        }
    }
    if (lane == 0) out_ct[(isL1 ? 1024 : 0) + u] = cst;
}

// ---------------------------------------------------------------------------
__global__ __launch_bounds__(256) void k_attn(
    const float* __restrict__ enc, float* __restrict__ attn)
{
    __shared__ __align__(16) float os[1024];
    __shared__ float ss[64];
    __shared__ float ws[64];
    const int t = blockIdx.x;
    const int tid = threadIdx.x;
    const float* orow = attn + (size_t)t * 2048;
    for (int i = tid; i < 1024; i += 256) os[i] = orow[i];
    __syncthreads();
    const int wave = tid >> 6, lane = tid & 63;
    for (int li = 0; li < 16; ++li) {
        const int l = wave * 16 + li;
        const float4* er = (const float4*)(enc + (size_t)l * 1024);
        float acc = 0.f;
        #pragma unroll
        for (int it = 0; it < 4; ++it) {
            float4 e4 = er[lane + 64 * it];
            float4 o4 = ((const float4*)os)[lane + 64 * it];
            acc = fmaf(e4.x, o4.x, fmaf(e4.y, o4.y, fmaf(e4.z, o4.z, fmaf(e4.w, o4.w, acc))));
        }
        #pragma unroll
        for (int off = 32; off; off >>= 1) acc += __shfl_xor(acc, off, 64);
        if (lane == 0) ss[l] = acc;
    }
    __syncthreads();
    if (tid < 64) {
        float v = ss[tid];
        float mx = v;
        #pragma unroll
        for (int off = 32; off; off >>= 1) mx = fmaxf(mx, __shfl_xor(mx, off, 64));
        float e = expf(v - mx);
        float sum = e;
        #pragma unroll
        for (int off = 32; off; off >>= 1) sum += __shfl_xor(sum, off, 64);
        ws[tid] = e / sum;
    }
    __syncthreads();
    #pragma unroll
    for (int c = 0; c < 4; ++c) {
        const int col = tid + c * 256;
        float acc = 0.f;
        for (int l = 0; l < 64; ++l) acc = fmaf(ws[l], enc[(size_t)l * 1024 + col], acc);
        attn[(size_t)t * 2048 + 1024 + col] = acc;
    }
}

// ---------------------------------------------------------------------------
extern "C" void kernel_launch(void* const* d_in, const int* in_sizes, int n_in,
                              void* d_out, int out_size, void* d_ws, size_t ws_size,
                              hipStream_t stream)
{
    const float* dec  = (const float*)d_in[0];
    const float* z    = (const float*)d_in[1];
    const float* enc  = (const float*)d_in[2];
    const float* h0   = (const float*)d_in[3];
    const float* c0   = (const float*)d_in[4];
    const float* W_ih = (const float*)d_in[5];
    const float* W_hh = (const float*)d_in[6];
    const float* b_ih = (const float*)d_in[7];
    const float* b_hh = (const float*)d_in[8];
    const float* W_fc = (const float*)d_in[9];
    const float* b_fc = (const float*)d_in[10];

    float* out    = (float*)d_out;
    float* logits = out + OUT_LOGITS;
    float* attn   = out + OUT_ATTN;
    float* out_ht = out + OUT_HT;
    float* out_ct = out + OUT_CT;

    char* wsb = (char*)d_ws;
    unsigned* bar          = (unsigned*)wsb;                      // 2 KB barrier region
    float* Gin0            = (float*)(wsb + 2048);
    float* h0buf           = Gin0 + 64 * 4096;
    float* h1buf           = h0buf + 2048;
    unsigned short* Xbf    = (unsigned short*)(h1buf + 2048);
    unsigned short* outs_bf = Xbf + 65536;

    hipMemsetAsync(bar, 0, 2048, stream);
    k_prep_x<<<256, 256, 0, stream>>>(dec, z, Xbf);
    k_gemm<<<64, 256, 0, stream>>>(W_ih, Xbf, b_ih, b_hh, Gin0, 4096);

    const float* a0 = W_ih; const float* a1 = W_hh; const float* a2 = b_ih;
    const float* a3 = b_hh; const float* a4 = h0;   const float* a5 = c0;
    const float* a6 = Gin0; float* a7 = h0buf; float* a8 = h1buf;
    unsigned* a9 = bar; float* a10 = attn; unsigned short* a11 = outs_bf;
    float* a12 = out_ht; float* a13 = out_ct;
    void* kargs[] = {&a0, &a1, &a2, &a3, &a4, &a5, &a6, &a7, &a8, &a9, &a10, &a11, &a12, &a13};
    hipLaunchCooperativeKernel((const void*)k_recur, dim3(RB), dim3(256), kargs, 0, stream);

    k_attn<<<64, 256, 0, stream>>>(enc, attn);
    k_gemm<<<500, 256, 0, stream>>>(W_fc, outs_bf, b_fc, nullptr, logits, 32000);
}

// Round 5
// 621.541 us; speedup vs baseline: 5.9912x; 1.1421x over previous
//
#include <hip/hip_runtime.h>
#include <cstdint>
#include <cstddef>

// B=1, S=64, L_ENC=64, E=512, Z=512, H=1024, NL=2, V=32000
// Outputs flat: logits [64][32000], attn_out [64][2048], hT [2][1024], cT [2][1024]

#define OUT_LOGITS 0
#define OUT_ATTN   2048000
#define OUT_HT     (2048000+131072)
#define OUT_CT     (OUT_HT+2048)
#define RB 512   // blocks in the persistent recurrence kernel

typedef short short8v __attribute__((ext_vector_type(8)));
typedef float floatx4 __attribute__((ext_vector_type(4)));

__device__ __forceinline__ float sigf_(float x) { return 1.0f / (1.0f + expf(-x)); }
__device__ __forceinline__ unsigned short f2bf(float x) {
    unsigned u = __float_as_uint(x);
    return (unsigned short)((u + 0x7fffu + ((u >> 16) & 1u)) >> 16);   // RNE
}
__device__ __forceinline__ unsigned pk2(float lo, float hi) {
    return (unsigned)f2bf(lo) | ((unsigned)f2bf(hi) << 16);
}
__device__ __forceinline__ float blo(unsigned u) { return __uint_as_float(u << 16); }
__device__ __forceinline__ float bhi(unsigned u) { return __uint_as_float(u & 0xffff0000u); }

// ---------------------------------------------------------------------------
__global__ __launch_bounds__(256) void k_prep_x(
    const float* __restrict__ dec, const float* __restrict__ z,
    unsigned short* __restrict__ Xbf)
{
    int i = blockIdx.x * 256 + threadIdx.x;      // grid 256 -> 65536
    int t = i >> 10, k = i & 1023;
    float v = (k < 512) ? dec[t * 512 + k] : z[k - 512];
    Xbf[i] = f2bf(v);
}

// ---------------------------------------------------------------------------
// LDS-staged MFMA GEMM: out[t][m] = sum_k A[m][k]*B[t][k] + bias1[m] (+bias2)
// A fp32 [M][1024] -> bf16 staged in LDS (BK=128 chunks, reg-double-buffered
// global loads). B bf16 [64][1024] direct from global (L2-hot).
// Block = 256 thr / 4 waves; block tile = 64 m-rows x 64 t. Grid = M/64.
// LDS row stride 68 dwords (136 bf16) -> conflict-spread b128 fragment reads.
// ---------------------------------------------------------------------------
__global__ __launch_bounds__(256) void k_gemm2(
    const float* __restrict__ A, const unsigned short* __restrict__ Bb,
    const float* __restrict__ bias1, const float* __restrict__ bias2,
    float* __restrict__ out, int M)
{
    __shared__ uint32_t As[64 * 68];               // 17.4 KB packed bf16 pairs
    const int tid = threadIdx.x, wave = tid >> 6, lane = tid & 63;
    const int m0 = blockIdx.x * 64;
    const int mr = lane & 15, kq = lane >> 4;
    const int lrow = tid >> 5;                     // 0..7 (row = lrow + 8j)
    const int lcol = tid & 31;                     // float4 col within 128-chunk
    floatx4 acc[4] = {};
    float4 rv[8];

    const float* abase = A + (size_t)m0 * 1024;
    #pragma unroll
    for (int j = 0; j < 8; ++j)
        rv[j] = *(const float4*)(abase + (size_t)(lrow + 8 * j) * 1024 + lcol * 4);

    const unsigned short* bfrag = Bb + (size_t)mr * 1024 + kq * 8;

    for (int c = 0; c < 8; ++c) {
        __syncthreads();
        #pragma unroll
        for (int j = 0; j < 8; ++j) {
            uint32_t* d = As + (lrow + 8 * j) * 68 + lcol * 2;
            d[0] = pk2(rv[j].x, rv[j].y);
            d[1] = pk2(rv[j].z, rv[j].w);
        }
        __syncthreads();
        if (c < 7) {
            #pragma unroll
            for (int j = 0; j < 8; ++j)
                rv[j] = *(const float4*)(abase + (size_t)(lrow + 8 * j) * 1024
                                         + (c + 1) * 128 + lcol * 4);
        }
        #pragma unroll
        for (int s = 0; s < 4; ++s) {
            short8v af = *(const short8v*)((const unsigned short*)As
                           + ((wave * 16 + mr) * 136 + s * 32 + kq * 8));
            #pragma unroll
            for (int g = 0; g < 4; ++g) {
                short8v bf = *(const short8v*)(bfrag + (size_t)g * 16 * 1024
                                               + c * 128 + s * 32);
                acc[g] = __builtin_amdgcn_mfma_f32_16x16x32_bf16(af, bf, acc[g], 0, 0, 0);
            }
        }
    }
    const int mo = m0 + wave * 16 + (kq << 2);     // m = wave*16 + quad*4 + reg
    float4 bv = *(const float4*)(bias1 + mo);
    if (bias2) {
        float4 b2 = *(const float4*)(bias2 + mo);
        bv.x += b2.x; bv.y += b2.y; bv.z += b2.z; bv.w += b2.w;
    }
    #pragma unroll
    for (int g = 0; g < 4; ++g) {
        const int t = g * 16 + mr;
        float4 o;
        o.x = acc[g][0] + bv.x; o.y = acc[g][1] + bv.y;
        o.z = acc[g][2] + bv.z; o.w = acc[g][3] + bv.w;
        *(float4*)(out + (size_t)t * M + mo) = o;
    }
}

// ---------------------------------------------------------------------------
// Tag-poll: each thread owns 4 {f32,val | u32,tag} 8-B pairs; reload until
// tag matches, then strip into LDS. Dataflow sync -> no barrier tree at all.
// ---------------------------------------------------------------------------
__device__ __forceinline__ void poll_tagged(
    const unsigned long long* __restrict__ src, float* __restrict__ dst,
    int tid, unsigned tag)
{
    unsigned long long v[4];
    #pragma unroll
    for (int j = 0; j < 4; ++j)
        v[j] = __hip_atomic_load(src + tid + 256 * j, __ATOMIC_RELAXED,
                                 __HIP_MEMORY_SCOPE_AGENT);
    unsigned need = 0xF;
    for (;;) {
        unsigned nx = 0;
        #pragma unroll
        for (int j = 0; j < 4; ++j) {
            if (need & (1u << j)) {
                if ((unsigned)(v[j] >> 32) == tag)
                    dst[tid + 256 * j] = __uint_as_float((unsigned)v[j]);
                else nx |= 1u << j;
            }
        }
        if (!nx) return;
        need = nx;
        __builtin_amdgcn_s_sleep(1);
        #pragma unroll
        for (int j = 0; j < 4; ++j)
            if (need & (1u << j))
                v[j] = __hip_atomic_load(src + tid + 256 * j, __ATOMIC_RELAXED,
                                         __HIP_MEMORY_SCOPE_AGENT);
    }
}

// ---------------------------------------------------------------------------
// Persistent recurrence: 512 blocks x 256 thr, weights LDS-resident bf16.
// Sync = tagged-data polling (producer 8-B {val,stage} atomic store; consumer
// polls). Per-block __syncthreads keeps L0/L1 waves lockstep => max skew 1
// stage => ping-pong parity + exact-tag match is race-free (tag k+2 write
// requires every block consumed tag k).
// ---------------------------------------------------------------------------
__global__ __launch_bounds__(256, 2) void k_recur(
    const float* __restrict__ W_ih, const float* __restrict__ W_hh,
    const float* __restrict__ b_ih, const float* __restrict__ b_hh,
    const float* __restrict__ h_init, const float* __restrict__ c_init,
    const float* __restrict__ Gin0,
    unsigned long long* __restrict__ h0t,   // [2][1024] tagged ping-pong
    unsigned long long* __restrict__ h1t,   // [2][1024]
    float* __restrict__ attn,
    unsigned short* __restrict__ outs_bf,
    float* __restrict__ out_ht, float* __restrict__ out_ct)
{
    __shared__ uint32_t wls[8 * 512 + 8 * 1024];   // 48 KB packed bf16 weights
    __shared__ __align__(16) float hs0[1024];      // h0[k-1]
    __shared__ __align__(16) float hs1[1024];      // h1[k-2]
    const int tid = threadIdx.x, wave = tid >> 6, lane = tid & 63;
    const bool isL1 = wave >= 2;
    const int u = blockIdx.x * 2 + (wave & 1);
    uint32_t* wbase = isL1 ? (wls + 8 * 512 + (wave & 1) * 4 * 1024)
                           : (wls + (wave & 1) * 4 * 512);

    // ---- stage weights into LDS as packed bf16 ----
    if (!isL1) {
        #pragma unroll
        for (int q = 0; q < 4; ++q) {
            const float* row = W_hh + (size_t)(q * 1024 + u) * 1024;
            uint32_t* dst = wbase + q * 512;
            #pragma unroll
            for (int jq = 0; jq < 2; ++jq) {
                float4 a = *(const float4*)(row + 512 * jq + 8 * lane);
                float4 b = *(const float4*)(row + 512 * jq + 8 * lane + 4);
                uint4 p;
                p.x = pk2(a.x, a.y); p.y = pk2(a.z, a.w);
                p.z = pk2(b.x, b.y); p.w = pk2(b.z, b.w);
                *(uint4*)(dst + jq * 256 + lane * 4) = p;
            }
        }
    } else {
        #pragma unroll
        for (int q = 0; q < 4; ++q) {
            const float* rowi = W_ih + (size_t)4096 * 1024 + (size_t)(q * 1024 + u) * 1024;
            const float* rowh = W_hh + (size_t)4096 * 1024 + (size_t)(q * 1024 + u) * 1024;
            uint32_t* dst = wbase + q * 1024;
            #pragma unroll
            for (int jq = 0; jq < 2; ++jq) {
                float4 a = *(const float4*)(rowi + 512 * jq + 8 * lane);
                float4 b = *(const float4*)(rowi + 512 * jq + 8 * lane + 4);
                uint4 p;
                p.x = pk2(a.x, a.y); p.y = pk2(a.z, a.w);
                p.z = pk2(b.x, b.y); p.w = pk2(b.z, b.w);
                *(uint4*)(dst + jq * 256 + lane * 4) = p;
                a = *(const float4*)(rowh + 512 * jq + 8 * lane);
                b = *(const float4*)(rowh + 512 * jq + 8 * lane + 4);
                p.x = pk2(a.x, a.y); p.y = pk2(a.z, a.w);
                p.z = pk2(b.x, b.y); p.w = pk2(b.z, b.w);
                *(uint4*)(dst + 512 + jq * 256 + lane * 4) = p;
            }
        }
    }

    float cst = 0.f, bi0 = 0.f, bi1 = 0.f, bi2 = 0.f, bi3 = 0.f;
    if (lane == 0) {
        cst = c_init[(isL1 ? 1024 : 0) + u];
        if (isL1) {
            bi0 = b_ih[4096 + u]        + b_hh[4096 + u];
            bi1 = b_ih[4096 + 1024 + u] + b_hh[4096 + 1024 + u];
            bi2 = b_ih[4096 + 2048 + u] + b_hh[4096 + 2048 + u];
            bi3 = b_ih[4096 + 3072 + u] + b_hh[4096 + 3072 + u];
        }
    }
    __syncthreads();

    for (int k = 0; k <= 64; ++k) {
        // ---- stage h vectors into LDS (tag-poll or init copy) ----
        if (k == 0) {
            #pragma unroll
            for (int j = 0; j < 4; ++j) hs0[tid + 256 * j] = h_init[tid + 256 * j];
        } else {
            poll_tagged(h0t + (size_t)((k - 1) & 1) * 1024, hs0, tid, (unsigned)k);
        }
        if (k == 1) {
            #pragma unroll
            for (int j = 0; j < 4; ++j) hs1[tid + 256 * j] = h_init[1024 + tid + 256 * j];
        } else if (k >= 2) {
            poll_tagged(h1t + (size_t)(k & 1) * 1024, hs1, tid, (unsigned)(k - 1));
        }
        __syncthreads();

        if (!isL1) {
            if (k < 64) {
                const int t = k;
                float4 h0v = ((const float4*)hs0)[2 * lane];
                float4 h1v = ((const float4*)hs0)[2 * lane + 1];
                float4 h2v = ((const float4*)hs0)[128 + 2 * lane];
                float4 h3v = ((const float4*)hs0)[128 + 2 * lane + 1];
                float g[4];
                #pragma unroll
                for (int q = 0; q < 4; ++q) {
                    const uint32_t* wr = wbase + q * 512;
                    uint4 wp = *(const uint4*)(wr + lane * 4);
                    float acc = 0.f;
                    acc = fmaf(blo(wp.x), h0v.x, acc); acc = fmaf(bhi(wp.x), h0v.y, acc);
                    acc = fmaf(blo(wp.y), h0v.z, acc); acc = fmaf(bhi(wp.y), h0v.w, acc);
                    acc = fmaf(blo(wp.z), h1v.x, acc); acc = fmaf(bhi(wp.z), h1v.y, acc);
                    acc = fmaf(blo(wp.w), h1v.z, acc); acc = fmaf(bhi(wp.w), h1v.w, acc);
                    wp = *(const uint4*)(wr + 256 + lane * 4);
                    acc = fmaf(blo(wp.x), h2v.x, acc); acc = fmaf(bhi(wp.x), h2v.y, acc);
                    acc = fmaf(blo(wp.y), h2v.z, acc); acc = fmaf(bhi(wp.y), h2v.w, acc);
                    acc = fmaf(blo(wp.z), h3v.x, acc); acc = fmaf(bhi(wp.z), h3v.y, acc);
                    acc = fmaf(blo(wp.w), h3v.z, acc); acc = fmaf(bhi(wp.w), h3v.w, acc);
                    #pragma unroll
                    for (int m = 32; m; m >>= 1) acc += __shfl_xor(acc, m, 64);
                    g[q] = acc;
                }
                if (lane == 0) {
                    const float* gin = Gin0 + (size_t)t * 4096;
                    float gi = g[0] + gin[u];
                    float gf = g[1] + gin[1024 + u];
                    float gg = g[2] + gin[2048 + u];
                    float go = g[3] + gin[3072 + u];
                    float c = sigf_(gf) * cst + sigf_(gi) * tanhf(gg);
                    float hn = sigf_(go) * tanhf(c);
                    cst = c;
                    unsigned long long pv = ((unsigned long long)(unsigned)(t + 1) << 32)
                                            | (unsigned long long)__float_as_uint(hn);
                    __hip_atomic_store(h0t + (size_t)(t & 1) * 1024 + u, pv,
                                       __ATOMIC_RELAXED, __HIP_MEMORY_SCOPE_AGENT);
                    if (t == 63) out_ht[u] = hn;
                }
            }
        } else {
            if (k >= 1) {
                const int t = k - 1;
                float4 x0v = ((const float4*)hs0)[2 * lane];
                float4 x1v = ((const float4*)hs0)[2 * lane + 1];
                float4 x2v = ((const float4*)hs0)[128 + 2 * lane];
                float4 x3v = ((const float4*)hs0)[128 + 2 * lane + 1];
                float4 h0v = ((const float4*)hs1)[2 * lane];
                float4 h1v = ((const float4*)hs1)[2 * lane + 1];
                float4 h2v = ((const float4*)hs1)[128 + 2 * lane];
                float4 h3v = ((const float4*)hs1)[128 + 2 * lane + 1];
                float g[4];
                #pragma unroll
                for (int q = 0; q < 4; ++q) {
                    const uint32_t* wr = wbase + q * 1024;
                    uint4 wp = *(const uint4*)(wr + lane * 4);
                    float acc = 0.f;
                    acc = fmaf(blo(wp.x), x0v.x, acc); acc = fmaf(bhi(wp.x), x0v.y, acc);
                    acc = fmaf(blo(wp.y), x0v.z, acc); acc = fmaf(bhi(wp.y), x0v.w, acc);
                    acc = fmaf(blo(wp.z), x1v.x, acc); acc = fmaf(bhi(wp.z), x1v.y, acc);
                    acc = fmaf(blo(wp.w), x1v.z, acc); acc = fmaf(bhi(wp.w), x1v.w, acc);
                    wp = *(const uint4*)(wr + 256 + lane * 4);
                    acc = fmaf(blo(wp.x), x2v.x, acc); acc = fmaf(bhi(wp.x), x2v.y, acc);
                    acc = fmaf(blo(wp.y), x2v.z, acc); acc = fmaf(bhi(wp.y), x2v.w, acc);
                    acc = fmaf(blo(wp.z), x3v.x, acc); acc = fmaf(bhi(wp.z), x3v.y, acc);
                    acc = fmaf(blo(wp.w), x3v.z, acc); acc = fmaf(bhi(wp.w), x3v.w, acc);
                    wp = *(const uint4*)(wr + 512 + lane * 4);
                    acc = fmaf(blo(wp.x), h0v.x, acc); acc = fmaf(bhi(wp.x), h0v.y, acc);
                    acc = fmaf(blo(wp.y), h0v.z, acc); acc = fmaf(bhi(wp.y), h0v.w, acc);
                    acc = fmaf(blo(wp.z), h1v.x, acc); acc = fmaf(bhi(wp.z), h1v.y, acc);
                    acc = fmaf(blo(wp.w), h1v.z, acc); acc = fmaf(bhi(wp.w), h1v.w, acc);
                    wp = *(const uint4*)(wr + 768 + lane * 4);
                    acc = fmaf(blo(wp.x), h2v.x, acc); acc = fmaf(bhi(wp.x), h2v.y, acc);
                    acc = fmaf(blo(wp.y), h2v.z, acc); acc = fmaf(bhi(wp.y), h2v.w, acc);
                    acc = fmaf(blo(wp.z), h3v.x, acc); acc = fmaf(bhi(wp.z), h3v.y, acc);
                    acc = fmaf(blo(wp.w), h3v.z, acc); acc = fmaf(bhi(wp.w), h3v.w, acc);
                    #pragma unroll
                    for (int m = 32; m; m >>= 1) acc += __shfl_xor(acc, m, 64);
                    g[q] = acc;
                }
                if (lane == 0) {
                    float gi = g[0] + bi0, gf = g[1] + bi1, gg = g[2] + bi2, go = g[3] + bi3;
                    float c = sigf_(gf) * cst + sigf_(gi) * tanhf(gg);
                    float hn = sigf_(go) * tanhf(c);
                    cst = c;
                    unsigned long long pv = ((unsigned long long)(unsigned)(t + 1) << 32)
                                            | (unsigned long long)__float_as_uint(hn);
                    __hip_atomic_store(h1t + (size_t)(t & 1) * 1024 + u, pv,
                                       __ATOMIC_RELAXED, __HIP_MEMORY_SCOPE_AGENT);
                    attn[(size_t)t * 2048 + u] = hn;
                    outs_bf[(size_t)t * 1024 + u] = f2bf(hn);
                    if (t == 63) out_ht[1024 + u] = hn;
                }
            }
        }
        __syncthreads();   // keep L0/L1 waves lockstep; protect hs0/hs1 reuse
    }
    if (lane == 0) out_ct[(isL1 ? 1024 : 0) + u] = cst;
}

// ---------------------------------------------------------------------------
__global__ __launch_bounds__(256) void k_attn(
    const float* __restrict__ enc, float* __restrict__ attn)
{
    __shared__ __align__(16) float os[1024];
    __shared__ float ss[64];
    __shared__ float ws[64];
    const int t = blockIdx.x;
    const int tid = threadIdx.x;
    const float* orow = attn + (size_t)t * 2048;
    for (int i = tid; i < 1024; i += 256) os[i] = orow[i];
    __syncthreads();
    const int wave = tid >> 6, lane = tid & 63;
    for (int li = 0; li < 16; ++li) {
        const int l = wave * 16 + li;
        const float4* er = (const float4*)(enc + (size_t)l * 1024);
        float acc = 0.f;
        #pragma unroll
        for (int it = 0; it < 4; ++it) {
            float4 e4 = er[lane + 64 * it];
            float4 o4 = ((const float4*)os)[lane + 64 * it];
            acc = fmaf(e4.x, o4.x, fmaf(e4.y, o4.y, fmaf(e4.z, o4.z, fmaf(e4.w, o4.w, acc))));
        }
        #pragma unroll
        for (int off = 32; off; off >>= 1) acc += __shfl_xor(acc, off, 64);
        if (lane == 0) ss[l] = acc;
    }
    __syncthreads();
    if (tid < 64) {
        float v = ss[tid];
        float mx = v;
        #pragma unroll
        for (int off = 32; off; off >>= 1) mx = fmaxf(mx, __shfl_xor(mx, off, 64));
        float e = expf(v - mx);
        float sum = e;
        #pragma unroll
        for (int off = 32; off; off >>= 1) sum += __shfl_xor(sum, off, 64);
        ws[tid] = e / sum;
    }
    __syncthreads();
    #pragma unroll
    for (int c = 0; c < 4; ++c) {
        const int col = tid + c * 256;
        float acc = 0.f;
        for (int l = 0; l < 64; ++l) acc = fmaf(ws[l], enc[(size_t)l * 1024 + col], acc);
        attn[(size_t)t * 2048 + 1024 + col] = acc;
    }
}

// ---------------------------------------------------------------------------
extern "C" void kernel_launch(void* const* d_in, const int* in_sizes, int n_in,
                              void* d_out, int out_size, void* d_ws, size_t ws_size,
                              hipStream_t stream)
{
    const float* dec  = (const float*)d_in[0];
    const float* z    = (const float*)d_in[1];
    const float* enc  = (const float*)d_in[2];
    const float* h0   = (const float*)d_in[3];
    const float* c0   = (const float*)d_in[4];
    const float* W_ih = (const float*)d_in[5];
    const float* W_hh = (const float*)d_in[6];
    const float* b_ih = (const float*)d_in[7];
    const float* b_hh = (const float*)d_in[8];
    const float* W_fc = (const float*)d_in[9];
    const float* b_fc = (const float*)d_in[10];

    float* out    = (float*)d_out;
    float* logits = out + OUT_LOGITS;
    float* attn   = out + OUT_ATTN;
    float* out_ht = out + OUT_HT;
    float* out_ct = out + OUT_CT;

    char* wsb = (char*)d_ws;
    float* Gin0             = (float*)wsb;                         // 1 MB
    unsigned long long* h0t = (unsigned long long*)(Gin0 + 64 * 4096);  // 16 KB
    unsigned long long* h1t = h0t + 2048;                          // 16 KB
    unsigned short* Xbf     = (unsigned short*)(h1t + 2048);       // 128 KB
    unsigned short* outs_bf = Xbf + 65536;                         // 128 KB

    k_prep_x<<<256, 256, 0, stream>>>(dec, z, Xbf);
    k_gemm2<<<64, 256, 0, stream>>>(W_ih, Xbf, b_ih, b_hh, Gin0, 4096);

    const float* a0 = W_ih; const float* a1 = W_hh; const float* a2 = b_ih;
    const float* a3 = b_hh; const float* a4 = h0;   const float* a5 = c0;
    const float* a6 = Gin0; unsigned long long* a7 = h0t; unsigned long long* a8 = h1t;
    float* a9 = attn; unsigned short* a10 = outs_bf;
    float* a11 = out_ht; float* a12 = out_ct;
    void* kargs[] = {&a0, &a1, &a2, &a3, &a4, &a5, &a6, &a7, &a8, &a9, &a10, &a11, &a12};
    hipLaunchCooperativeKernel((const void*)k_recur, dim3(RB), dim3(256), kargs, 0, stream);

    k_attn<<<64, 256, 0, stream>>>(enc, attn);
    k_gemm2<<<500, 256, 0, stream>>>(W_fc, outs_bf, b_fc, nullptr, logits, 32000);
}